// Round 1
// baseline (9111.461 us; speedup 1.0000x reference)
//
#include <hip/hip_runtime.h>
#include <hip/hip_bf16.h>

// Problem constants (match reference)
#define B_GR   128
#define GWID   30
#define IWID   90
#define C_IN   32
#define R_REL  8
#define NBAS   4
#define N_NODES (B_GR*GWID*GWID)   // 115200
#define E_EDGES (N_NODES*8)        // 921600
#define NEG_SLOPE 0.01f

#define ELIST_CAP ((E_EDGES + R_REL*64 + 63)/64*64)   // 922112
#define NTILES (ELIST_CAP/64)                          // 14408

// ---------------- edge bucketing (etype fixed across layers; done once) ----------
__global__ void k_count(const int* __restrict__ et, int* __restrict__ cnt) {
    int e = blockIdx.x*256 + threadIdx.x;
    if (e < E_EDGES) atomicAdd(&cnt[et[e]], 1);
}
__global__ void k_prefix(const int* __restrict__ cnt, int* __restrict__ offs, int* __restrict__ cursor) {
    if (blockIdx.x==0 && threadIdx.x==0) {
        int acc = 0;
        for (int r = 0; r < R_REL; ++r) {
            offs[r] = acc; cursor[r] = acc;
            acc += ((cnt[r] + 63)/64)*64;   // pad each bucket to 64-edge tiles
        }
        offs[R_REL] = acc;
    }
}
__global__ void k_scatter(const int* __restrict__ et, int* __restrict__ cursor, int* __restrict__ elist) {
    int e = blockIdx.x*256 + threadIdx.x;
    if (e < E_EDGES) {
        int pos = atomicAdd(&cursor[et[e]], 1);
        elist[pos] = e;
    }
}

// ---------------- W_r = sum_b comp[r,b] * bases[b]  -> (R, din, dout) ----------
__global__ void k_wcomp(const float* __restrict__ bases, const float* __restrict__ comp,
                        float* __restrict__ W, int din, int dout) {
    int idx = blockIdx.x*256 + threadIdx.x;
    int tot = R_REL*din*dout;
    if (idx >= tot) return;
    int r = idx/(din*dout), rem = idx%(din*dout);
    float acc = 0.f;
    #pragma unroll
    for (int b = 0; b < NBAS; ++b) acc += comp[r*NBAS + b]*bases[b*din*dout + rem];
    W[idx] = acc;
}

// ---------------- self-loop GEMM: out = h @ loopw + bias (init of agg) ----------
template<int DIN, int DOUT>
__global__ __launch_bounds__(256) void k_selfgemm(const float* __restrict__ h,
        const float* __restrict__ loopw, const float* __restrict__ bias,
        float* __restrict__ out) {
    __shared__ float As[64][DIN+1];
    __shared__ float Bs[DIN][DOUT];
    const int tid = threadIdx.x;
    const int row0 = blockIdx.x*64;
    for (int idx = tid; idx < 64*DIN; idx += 256) {
        int r = idx/DIN, k = idx%DIN;
        As[r][k] = h[(size_t)(row0+r)*DIN + k];
    }
    for (int idx = tid; idx < DIN*DOUT; idx += 256)
        Bs[idx/DOUT][idx%DOUT] = loopw[idx];
    __syncthreads();

    constexpr int TX = DOUT/4;     // threads across cols (float4 each)
    constexpr int TY = 256/TX;     // threads across rows
    constexpr int RPT = 64/TY;     // rows per thread
    const int tx = tid % TX, ty = tid / TX;
    float acc[RPT][4];
    #pragma unroll
    for (int i = 0; i < RPT; ++i) { acc[i][0]=acc[i][1]=acc[i][2]=acc[i][3]=0.f; }

    #pragma unroll 8
    for (int k = 0; k < DIN; ++k) {
        float4 bv = *reinterpret_cast<const float4*>(&Bs[k][tx*4]);
        #pragma unroll
        for (int i = 0; i < RPT; ++i) {
            float a = As[ty*RPT+i][k];
            acc[i][0] += a*bv.x; acc[i][1] += a*bv.y;
            acc[i][2] += a*bv.z; acc[i][3] += a*bv.w;
        }
    }
    float b0 = bias[tx*4+0], b1 = bias[tx*4+1], b2 = bias[tx*4+2], b3 = bias[tx*4+3];
    #pragma unroll
    for (int i = 0; i < RPT; ++i) {
        float* o = &out[(size_t)(row0 + ty*RPT + i)*DOUT + tx*4];
        o[0] = acc[i][0]+b0; o[1] = acc[i][1]+b1; o[2] = acc[i][2]+b2; o[3] = acc[i][3]+b3;
    }
}

// ---------------- edge gather-GEMM: agg[dst] += (h[src]*norm) @ W[etype] --------
template<int DIN, int DOUT>
__global__ __launch_bounds__(256) void k_edgegemm(const float* __restrict__ h,
        const float* __restrict__ W, const int* __restrict__ src, const int* __restrict__ dst,
        const float* __restrict__ norm, const int* __restrict__ elist,
        const int* __restrict__ offs, float* __restrict__ agg) {
    __shared__ float As[64][DIN+1];
    __shared__ float Bs[DIN][DOUT];
    __shared__ int   s_e[64];
    __shared__ int   s_src[64];
    __shared__ int   s_dst[64];
    __shared__ float s_norm[64];
    __shared__ int   s_et;
    const int tid = threadIdx.x;
    const int pos0 = blockIdx.x*64;

    if (tid == 0) {
        int r = R_REL-1;
        #pragma unroll
        for (int i = 0; i < R_REL; ++i)
            if (pos0 >= offs[i] && pos0 < offs[i+1]) { r = i; break; }
        s_et = r;
    }
    if (tid < 64) {
        int e = elist[pos0 + tid];
        s_e[tid] = e;
        s_src[tid]  = (e >= 0) ? src[e]  : 0;
        s_dst[tid]  = (e >= 0) ? dst[e]  : 0;
        s_norm[tid] = (e >= 0) ? norm[e] : 0.f;
    }
    __syncthreads();

    const float* Wb = W + (size_t)s_et*DIN*DOUT;
    for (int idx = tid; idx < 64*DIN; idx += 256) {
        int r = idx/DIN, k = idx%DIN;
        As[r][k] = h[(size_t)s_src[r]*DIN + k] * s_norm[r];   // dummy rows: norm=0 -> zero row
    }
    for (int idx = tid; idx < DIN*DOUT; idx += 256)
        Bs[idx/DOUT][idx%DOUT] = Wb[idx];
    __syncthreads();

    constexpr int TX = DOUT/4;
    constexpr int TY = 256/TX;
    constexpr int RPT = 64/TY;
    const int tx = tid % TX, ty = tid / TX;
    float acc[RPT][4];
    #pragma unroll
    for (int i = 0; i < RPT; ++i) { acc[i][0]=acc[i][1]=acc[i][2]=acc[i][3]=0.f; }

    #pragma unroll 8
    for (int k = 0; k < DIN; ++k) {
        float4 bv = *reinterpret_cast<const float4*>(&Bs[k][tx*4]);
        #pragma unroll
        for (int i = 0; i < RPT; ++i) {
            float a = As[ty*RPT+i][k];
            acc[i][0] += a*bv.x; acc[i][1] += a*bv.y;
            acc[i][2] += a*bv.z; acc[i][3] += a*bv.w;
        }
    }
    #pragma unroll
    for (int i = 0; i < RPT; ++i) {
        int r = ty*RPT + i;
        if (s_e[r] >= 0) {
            float* o = &agg[(size_t)s_dst[r]*DOUT + tx*4];
            atomicAdd(o+0, acc[i][0]); atomicAdd(o+1, acc[i][1]);
            atomicAdd(o+2, acc[i][2]); atomicAdd(o+3, acc[i][3]);
        }
    }
}

// ---------------- activations ----------------
__global__ void k_leaky(float* __restrict__ x, int n) {
    int i = blockIdx.x*256 + threadIdx.x;
    if (i < n) { float v = x[i]; x[i] = (v >= 0.f) ? v : NEG_SLOPE*v; }
}
__global__ void k_sigmoid(float* __restrict__ x, int n) {
    int i = blockIdx.x*256 + threadIdx.x;
    if (i < n) { float v = x[i]; x[i] = 1.f/(1.f + __expf(-v)); }
}

// ---------------- conv-transpose decoder + sigmoid ----------------
// logits layout: (B, GW, GW, 32) channel-last. w: torch (Cin=32, 1, 7, 7).
// y[b,oy,ox] = sigmoid( cb + sum over taps where ky = oy+2-3*iy, kx = ox+2-3*ix )
__global__ __launch_bounds__(256) void k_convt(const float* __restrict__ logits,
        const float* __restrict__ w, const float* __restrict__ cb, float* __restrict__ out) {
    __shared__ float s_w[49*32];  // [tap][c] transposed for float4 channel access
    const int tid = threadIdx.x;
    for (int idx = tid; idx < 49*32; idx += 256) {
        int tap = idx/32, c = idx%32;
        s_w[tap*32 + c] = w[c*49 + tap];
    }
    __syncthreads();
    int g = blockIdx.x*256 + tid;
    if (g >= B_GR*IWID*IWID) return;
    int b = g/(IWID*IWID);
    int rem = g%(IWID*IWID);
    int oy = rem/IWID, ox = rem%IWID;

    float acc = cb[0];
    for (int ky = 0; ky < 7; ++ky) {
        int t = oy + 2 - ky;
        if (t < 0 || (t % 3) != 0) continue;
        int iy = t/3; if (iy >= GWID) continue;
        for (int kx = 0; kx < 7; ++kx) {
            int u = ox + 2 - kx;
            if (u < 0 || (u % 3) != 0) continue;
            int ix = u/3; if (ix >= GWID) continue;
            const float4* xp = reinterpret_cast<const float4*>(&logits[(((size_t)b*GWID + iy)*GWID + ix)*32]);
            const float4* wp = reinterpret_cast<const float4*>(&s_w[(ky*7 + kx)*32]);
            #pragma unroll
            for (int c4 = 0; c4 < 8; ++c4) {
                float4 xv = xp[c4], wv = wp[c4];
                acc += xv.x*wv.x + xv.y*wv.y + xv.z*wv.z + xv.w*wv.w;
            }
        }
    }
    out[g] = 1.f/(1.f + __expf(-acc));
}

// ---------------- host ----------------
extern "C" void kernel_launch(void* const* d_in, const int* in_sizes, int n_in,
                              void* d_out, int out_size, void* d_ws, size_t ws_size,
                              hipStream_t stream) {
    const float* features = (const float*)d_in[0];
    const int*   src      = (const int*)  d_in[1];
    const int*   dst      = (const int*)  d_in[2];
    const int*   etypes   = (const int*)  d_in[3];
    const float* norm     = (const float*)d_in[4];
    const float* bases0 = (const float*)d_in[5];
    const float* comp0  = (const float*)d_in[6];
    const float* loop0  = (const float*)d_in[7];
    const float* bias0  = (const float*)d_in[8];
    const float* bases1 = (const float*)d_in[9];
    const float* comp1  = (const float*)d_in[10];
    const float* loop1  = (const float*)d_in[11];
    const float* bias1  = (const float*)d_in[12];
    const float* bases2 = (const float*)d_in[13];
    const float* comp2  = (const float*)d_in[14];
    const float* loop2  = (const float*)d_in[15];
    const float* bias2  = (const float*)d_in[16];
    const float* conv_w = (const float*)d_in[17];
    const float* conv_b = (const float*)d_in[18];
    float* out = (float*)d_out;

    // workspace carve-up (floats). Total ~78 MB.
    float* ws = (float*)d_ws;
    float* W0     = ws;                         // 8*32*64 = 16384
    float* W1     = W0 + 16384;                 // 8*64*64 = 32768
    float* W2     = W1 + 32768;                 // 8*64*32 = 16384
    float* h1     = W2 + 16384;                 // N*64
    float* h2     = h1 + (size_t)N_NODES*64;    // N*64
    float* logits = h2 + (size_t)N_NODES*64;    // N*32
    int*   elist  = (int*)(logits + (size_t)N_NODES*32);   // ELIST_CAP
    int*   cnt    = elist + ELIST_CAP;          // 8
    int*   offs   = cnt + 8;                    // 9
    int*   cursor = offs + 9;                   // 8

    // ---- bucket edges by etype (reused for all 3 layers) ----
    hipMemsetAsync(cnt, 0, 8*sizeof(int), stream);
    hipMemsetAsync(elist, 0xFF, (size_t)ELIST_CAP*sizeof(int), stream);  // -1
    int ebl = (E_EDGES + 255)/256;
    k_count  <<<ebl, 256, 0, stream>>>(etypes, cnt);
    k_prefix <<<1, 64, 0, stream>>>(cnt, offs, cursor);
    k_scatter<<<ebl, 256, 0, stream>>>(etypes, cursor, elist);

    // ---- basis contraction ----
    k_wcomp<<<(R_REL*32*64 + 255)/256, 256, 0, stream>>>(bases0, comp0, W0, 32, 64);
    k_wcomp<<<(R_REL*64*64 + 255)/256, 256, 0, stream>>>(bases1, comp1, W1, 64, 64);
    k_wcomp<<<(R_REL*64*32 + 255)/256, 256, 0, stream>>>(bases2, comp2, W2, 64, 32);

    const int NROWT = N_NODES/64;   // 1800

    // ---- layer 0: 32 -> 64, leaky ----
    k_selfgemm<32,64><<<NROWT, 256, 0, stream>>>(features, loop0, bias0, h1);
    k_edgegemm<32,64><<<NTILES, 256, 0, stream>>>(features, W0, src, dst, norm, elist, offs, h1);
    k_leaky<<<(N_NODES*64)/256, 256, 0, stream>>>(h1, N_NODES*64);

    // ---- layer 1: 64 -> 64, leaky ----
    k_selfgemm<64,64><<<NROWT, 256, 0, stream>>>(h1, loop1, bias1, h2);
    k_edgegemm<64,64><<<NTILES, 256, 0, stream>>>(h1, W1, src, dst, norm, elist, offs, h2);
    k_leaky<<<(N_NODES*64)/256, 256, 0, stream>>>(h2, N_NODES*64);

    // ---- layer 2: 64 -> 32, sigmoid ----
    k_selfgemm<64,32><<<NROWT, 256, 0, stream>>>(h2, loop2, bias2, logits);
    k_edgegemm<64,32><<<NTILES, 256, 0, stream>>>(h2, W2, src, dst, norm, elist, offs, logits);
    k_sigmoid<<<(N_NODES*32)/256, 256, 0, stream>>>(logits, N_NODES*32);

    // ---- decoder ----
    k_convt<<<(B_GR*IWID*IWID + 255)/256, 256, 0, stream>>>(logits, conv_w, conv_b, out);
}

// Round 2
// 2233.937 us; speedup vs baseline: 4.0787x; 4.0787x over previous
//
#include <hip/hip_runtime.h>
#include <hip/hip_bf16.h>

// Problem constants (match reference)
#define B_GR   128
#define GWID   30
#define IWID   90
#define C_IN   32
#define R_REL  8
#define NBAS   4
#define N_NODES (B_GR*GWID*GWID)   // 115200
#define E_EDGES (N_NODES*8)        // 921600
#define NEG_SLOPE 0.01f

#define ELIST_CAP ((E_EDGES + R_REL*64 + 63)/64*64)   // 922112
#define NTILES (ELIST_CAP/64)                          // 14408

#define NCHUNK 256
#define CHUNK  (E_EDGES/NCHUNK)    // 3600 exactly

// ================= contention-free counting sort by etype =================
// k_hist: per-chunk histogram. LDS sub-counters (8 relations x 32 columns)
// keep same-address LDS atomic collisions to ~8-way max.
__global__ __launch_bounds__(256) void k_hist(const int* __restrict__ et,
                                              int* __restrict__ hist_g) {
    __shared__ int h[R_REL][33];
    const int tid = threadIdx.x, b = blockIdx.x;
    for (int i = tid; i < R_REL*33; i += 256) ((int*)h)[i] = 0;
    __syncthreads();
    const int base = b*CHUNK;
    for (int i = tid; i < CHUNK; i += 256) {
        int r = et[base + i];
        atomicAdd(&h[r][tid & 31], 1);
    }
    __syncthreads();
    if (tid < R_REL) {
        int s = 0;
        #pragma unroll
        for (int c = 0; c < 32; ++c) s += h[tid][c];
        hist_g[tid*NCHUNK + b] = s;   // relation-major for the scan
    }
}

// k_scan8: one block. For each relation: exclusive scan over 256 chunk counts,
// add running 64-padded bucket offset -> per-(relation,chunk) base + offs[].
__global__ __launch_bounds__(256) void k_scan8(const int* __restrict__ hist_g,
                                               int* __restrict__ base_g,
                                               int* __restrict__ offs) {
    __shared__ int s[NCHUNK];
    __shared__ int s2[NCHUNK];
    const int tid = threadIdx.x;
    int acc = 0;
    for (int r = 0; r < R_REL; ++r) {
        int v = hist_g[r*NCHUNK + tid];
        s[tid] = v;
        __syncthreads();
        // Hillis-Steele inclusive scan (ping-pong)
        int* cur = s; int* nxt = s2;
        for (int d = 1; d < NCHUNK; d <<= 1) {
            int val = cur[tid];
            if (tid >= d) val += cur[tid - d];
            nxt[tid] = val;
            __syncthreads();
            int* t = cur; cur = nxt; nxt = t;
        }
        int incl = cur[tid];
        base_g[r*NCHUNK + tid] = acc + incl - v;   // exclusive + bucket offset
        if (tid == 0) offs[r] = acc;
        int total = cur[NCHUNK-1];
        acc += ((total + 63)/64)*64;               // pad bucket to 64-edge tiles
        __syncthreads();
    }
    if (tid == 0) offs[R_REL] = acc;
}

// k_scatter2: re-read chunk, place each edge via LDS cursors (no global atomics).
__global__ __launch_bounds__(256) void k_scatter2(const int* __restrict__ et,
                                                  const int* __restrict__ base_g,
                                                  int* __restrict__ elist) {
    __shared__ int cur[R_REL];
    const int tid = threadIdx.x, b = blockIdx.x;
    if (tid < R_REL) cur[tid] = base_g[tid*NCHUNK + b];
    __syncthreads();
    const int base = b*CHUNK;
    for (int i = tid; i < CHUNK; i += 256) {
        int e = base + i;
        int r = et[e];
        int pos = atomicAdd(&cur[r], 1);
        elist[pos] = e;
    }
}

// ---------------- W_r = sum_b comp[r,b] * bases[b]  -> (R, din, dout) ----------
__global__ void k_wcomp(const float* __restrict__ bases, const float* __restrict__ comp,
                        float* __restrict__ W, int din, int dout) {
    int idx = blockIdx.x*256 + threadIdx.x;
    int tot = R_REL*din*dout;
    if (idx >= tot) return;
    int r = idx/(din*dout), rem = idx%(din*dout);
    float acc = 0.f;
    #pragma unroll
    for (int b = 0; b < NBAS; ++b) acc += comp[r*NBAS + b]*bases[b*din*dout + rem];
    W[idx] = acc;
}

// ---------------- self-loop GEMM: out = h @ loopw + bias (init of agg) ----------
template<int DIN, int DOUT>
__global__ __launch_bounds__(256) void k_selfgemm(const float* __restrict__ h,
        const float* __restrict__ loopw, const float* __restrict__ bias,
        float* __restrict__ out) {
    __shared__ float As[64][DIN+1];
    __shared__ float Bs[DIN][DOUT];
    const int tid = threadIdx.x;
    const int row0 = blockIdx.x*64;
    for (int idx = tid; idx < 64*DIN; idx += 256) {
        int r = idx/DIN, k = idx%DIN;
        As[r][k] = h[(size_t)(row0+r)*DIN + k];
    }
    for (int idx = tid; idx < DIN*DOUT; idx += 256)
        Bs[idx/DOUT][idx%DOUT] = loopw[idx];
    __syncthreads();

    constexpr int TX = DOUT/4;     // threads across cols (float4 each)
    constexpr int TY = 256/TX;     // threads across rows
    constexpr int RPT = 64/TY;     // rows per thread
    const int tx = tid % TX, ty = tid / TX;
    float acc[RPT][4];
    #pragma unroll
    for (int i = 0; i < RPT; ++i) { acc[i][0]=acc[i][1]=acc[i][2]=acc[i][3]=0.f; }

    #pragma unroll 8
    for (int k = 0; k < DIN; ++k) {
        float4 bv = *reinterpret_cast<const float4*>(&Bs[k][tx*4]);
        #pragma unroll
        for (int i = 0; i < RPT; ++i) {
            float a = As[ty*RPT+i][k];
            acc[i][0] += a*bv.x; acc[i][1] += a*bv.y;
            acc[i][2] += a*bv.z; acc[i][3] += a*bv.w;
        }
    }
    float b0 = bias[tx*4+0], b1 = bias[tx*4+1], b2 = bias[tx*4+2], b3 = bias[tx*4+3];
    #pragma unroll
    for (int i = 0; i < RPT; ++i) {
        float* o = &out[(size_t)(row0 + ty*RPT + i)*DOUT + tx*4];
        o[0] = acc[i][0]+b0; o[1] = acc[i][1]+b1; o[2] = acc[i][2]+b2; o[3] = acc[i][3]+b3;
    }
}

// ---------------- edge gather-GEMM: agg[dst] += (h[src]*norm) @ W[etype] --------
template<int DIN, int DOUT>
__global__ __launch_bounds__(256) void k_edgegemm(const float* __restrict__ h,
        const float* __restrict__ W, const int* __restrict__ src, const int* __restrict__ dst,
        const float* __restrict__ norm, const int* __restrict__ elist,
        const int* __restrict__ offs, float* __restrict__ agg) {
    __shared__ float As[64][DIN+1];
    __shared__ float Bs[DIN][DOUT];
    __shared__ int   s_e[64];
    __shared__ int   s_src[64];
    __shared__ int   s_dst[64];
    __shared__ float s_norm[64];
    __shared__ int   s_et;
    const int tid = threadIdx.x;
    const int pos0 = blockIdx.x*64;

    if (tid == 0) {
        int r = R_REL-1;
        #pragma unroll
        for (int i = 0; i < R_REL; ++i)
            if (pos0 >= offs[i] && pos0 < offs[i+1]) { r = i; break; }
        s_et = r;
    }
    if (tid < 64) {
        int e = elist[pos0 + tid];
        s_e[tid] = e;
        s_src[tid]  = (e >= 0) ? src[e]  : 0;
        s_dst[tid]  = (e >= 0) ? dst[e]  : 0;
        s_norm[tid] = (e >= 0) ? norm[e] : 0.f;
    }
    __syncthreads();

    const float* Wb = W + (size_t)s_et*DIN*DOUT;
    for (int idx = tid; idx < 64*DIN; idx += 256) {
        int r = idx/DIN, k = idx%DIN;
        As[r][k] = h[(size_t)s_src[r]*DIN + k] * s_norm[r];   // dummy rows: norm=0 -> zero row
    }
    for (int idx = tid; idx < DIN*DOUT; idx += 256)
        Bs[idx/DOUT][idx%DOUT] = Wb[idx];
    __syncthreads();

    constexpr int TX = DOUT/4;
    constexpr int TY = 256/TX;
    constexpr int RPT = 64/TY;
    const int tx = tid % TX, ty = tid / TX;
    float acc[RPT][4];
    #pragma unroll
    for (int i = 0; i < RPT; ++i) { acc[i][0]=acc[i][1]=acc[i][2]=acc[i][3]=0.f; }

    #pragma unroll 8
    for (int k = 0; k < DIN; ++k) {
        float4 bv = *reinterpret_cast<const float4*>(&Bs[k][tx*4]);
        #pragma unroll
        for (int i = 0; i < RPT; ++i) {
            float a = As[ty*RPT+i][k];
            acc[i][0] += a*bv.x; acc[i][1] += a*bv.y;
            acc[i][2] += a*bv.z; acc[i][3] += a*bv.w;
        }
    }
    #pragma unroll
    for (int i = 0; i < RPT; ++i) {
        int r = ty*RPT + i;
        if (s_e[r] >= 0) {
            float* o = &agg[(size_t)s_dst[r]*DOUT + tx*4];
            atomicAdd(o+0, acc[i][0]); atomicAdd(o+1, acc[i][1]);
            atomicAdd(o+2, acc[i][2]); atomicAdd(o+3, acc[i][3]);
        }
    }
}

// ---------------- activations ----------------
__global__ void k_leaky(float* __restrict__ x, int n) {
    int i = blockIdx.x*256 + threadIdx.x;
    if (i < n) { float v = x[i]; x[i] = (v >= 0.f) ? v : NEG_SLOPE*v; }
}
__global__ void k_sigmoid(float* __restrict__ x, int n) {
    int i = blockIdx.x*256 + threadIdx.x;
    if (i < n) { float v = x[i]; x[i] = 1.f/(1.f + __expf(-v)); }
}

// ---------------- conv-transpose decoder + sigmoid ----------------
__global__ __launch_bounds__(256) void k_convt(const float* __restrict__ logits,
        const float* __restrict__ w, const float* __restrict__ cb, float* __restrict__ out) {
    __shared__ float s_w[49*32];  // [tap][c] transposed for float4 channel access
    const int tid = threadIdx.x;
    for (int idx = tid; idx < 49*32; idx += 256) {
        int tap = idx/32, c = idx%32;
        s_w[tap*32 + c] = w[c*49 + tap];
    }
    __syncthreads();
    int g = blockIdx.x*256 + tid;
    if (g >= B_GR*IWID*IWID) return;
    int b = g/(IWID*IWID);
    int rem = g%(IWID*IWID);
    int oy = rem/IWID, ox = rem%IWID;

    float acc = cb[0];
    for (int ky = 0; ky < 7; ++ky) {
        int t = oy + 2 - ky;
        if (t < 0 || (t % 3) != 0) continue;
        int iy = t/3; if (iy >= GWID) continue;
        for (int kx = 0; kx < 7; ++kx) {
            int u = ox + 2 - kx;
            if (u < 0 || (u % 3) != 0) continue;
            int ix = u/3; if (ix >= GWID) continue;
            const float4* xp = reinterpret_cast<const float4*>(&logits[(((size_t)b*GWID + iy)*GWID + ix)*32]);
            const float4* wp = reinterpret_cast<const float4*>(&s_w[(ky*7 + kx)*32]);
            #pragma unroll
            for (int c4 = 0; c4 < 8; ++c4) {
                float4 xv = xp[c4], wv = wp[c4];
                acc += xv.x*wv.x + xv.y*wv.y + xv.z*wv.z + xv.w*wv.w;
            }
        }
    }
    out[g] = 1.f/(1.f + __expf(-acc));
}

// ---------------- host ----------------
extern "C" void kernel_launch(void* const* d_in, const int* in_sizes, int n_in,
                              void* d_out, int out_size, void* d_ws, size_t ws_size,
                              hipStream_t stream) {
    const float* features = (const float*)d_in[0];
    const int*   src      = (const int*)  d_in[1];
    const int*   dst      = (const int*)  d_in[2];
    const int*   etypes   = (const int*)  d_in[3];
    const float* norm     = (const float*)d_in[4];
    const float* bases0 = (const float*)d_in[5];
    const float* comp0  = (const float*)d_in[6];
    const float* loop0  = (const float*)d_in[7];
    const float* bias0  = (const float*)d_in[8];
    const float* bases1 = (const float*)d_in[9];
    const float* comp1  = (const float*)d_in[10];
    const float* loop1  = (const float*)d_in[11];
    const float* bias1  = (const float*)d_in[12];
    const float* bases2 = (const float*)d_in[13];
    const float* comp2  = (const float*)d_in[14];
    const float* loop2  = (const float*)d_in[15];
    const float* bias2  = (const float*)d_in[16];
    const float* conv_w = (const float*)d_in[17];
    const float* conv_b = (const float*)d_in[18];
    float* out = (float*)d_out;

    // workspace carve-up (floats). Total ~78 MB.
    float* ws = (float*)d_ws;
    float* W0     = ws;                         // 8*32*64 = 16384
    float* W1     = W0 + 16384;                 // 8*64*64 = 32768
    float* W2     = W1 + 32768;                 // 8*64*32 = 16384
    float* h1     = W2 + 16384;                 // N*64
    float* h2     = h1 + (size_t)N_NODES*64;    // N*64
    float* logits = h2 + (size_t)N_NODES*64;    // N*32
    int*   elist  = (int*)(logits + (size_t)N_NODES*32);   // ELIST_CAP
    int*   hist_g = elist + ELIST_CAP;          // R*NCHUNK = 2048
    int*   base_g = hist_g + R_REL*NCHUNK;      // 2048
    int*   offs   = base_g + R_REL*NCHUNK;      // 9

    // ---- bucket edges by etype: contention-free counting sort ----
    hipMemsetAsync(elist, 0xFF, (size_t)ELIST_CAP*sizeof(int), stream);  // -1
    k_hist    <<<NCHUNK, 256, 0, stream>>>(etypes, hist_g);
    k_scan8   <<<1, NCHUNK, 0, stream>>>(hist_g, base_g, offs);
    k_scatter2<<<NCHUNK, 256, 0, stream>>>(etypes, base_g, elist);

    // ---- basis contraction ----
    k_wcomp<<<(R_REL*32*64 + 255)/256, 256, 0, stream>>>(bases0, comp0, W0, 32, 64);
    k_wcomp<<<(R_REL*64*64 + 255)/256, 256, 0, stream>>>(bases1, comp1, W1, 64, 64);
    k_wcomp<<<(R_REL*64*32 + 255)/256, 256, 0, stream>>>(bases2, comp2, W2, 64, 32);

    const int NROWT = N_NODES/64;   // 1800

    // ---- layer 0: 32 -> 64, leaky ----
    k_selfgemm<32,64><<<NROWT, 256, 0, stream>>>(features, loop0, bias0, h1);
    k_edgegemm<32,64><<<NTILES, 256, 0, stream>>>(features, W0, src, dst, norm, elist, offs, h1);
    k_leaky<<<(N_NODES*64)/256, 256, 0, stream>>>(h1, N_NODES*64);

    // ---- layer 1: 64 -> 64, leaky ----
    k_selfgemm<64,64><<<NROWT, 256, 0, stream>>>(h1, loop1, bias1, h2);
    k_edgegemm<64,64><<<NTILES, 256, 0, stream>>>(h1, W1, src, dst, norm, elist, offs, h2);
    k_leaky<<<(N_NODES*64)/256, 256, 0, stream>>>(h2, N_NODES*64);

    // ---- layer 2: 64 -> 32, sigmoid ----
    k_selfgemm<64,32><<<NROWT, 256, 0, stream>>>(h2, loop2, bias2, logits);
    k_edgegemm<64,32><<<NTILES, 256, 0, stream>>>(h2, W2, src, dst, norm, elist, offs, logits);
    k_sigmoid<<<(N_NODES*32)/256, 256, 0, stream>>>(logits, N_NODES*32);

    // ---- decoder ----
    k_convt<<<(B_GR*IWID*IWID + 255)/256, 256, 0, stream>>>(logits, conv_w, conv_b, out);
}